// Round 4
// baseline (1447.522 us; speedup 1.0000x reference)
//
#include <hip/hip_runtime.h>
#include <cstdint>
#include <cstddef>

#define N_NODES 20000

typedef float f32x4 __attribute__((ext_vector_type(4)));
typedef unsigned short u16x8 __attribute__((ext_vector_type(8)));
typedef __bf16 bf16x8 __attribute__((ext_vector_type(8)));

static __device__ __forceinline__ bf16x8 asbf(u16x8 u) {
    return __builtin_bit_cast(bf16x8, u);
}
static __device__ __forceinline__ unsigned short f2b(float f) {
    return __builtin_bit_cast(unsigned short, (__bf16)f);   // RNE, fuses to v_cvt_pk_bf16_f32
}
static __device__ __forceinline__ float b2f(unsigned short u) {
    return __builtin_bit_cast(float, (unsigned)u << 16);
}
static __device__ __forceinline__ u16x8 pack8(f32x4 a, f32x4 b) {
    u16x8 r;
#pragma unroll
    for (int e = 0; e < 4; e++) {
        r[e]     = f2b(a[e]);
        r[4 + e] = f2b(b[e]);
    }
    return r;
}
static __device__ __forceinline__ float sigm(float z) {
    return 1.f / (1.f + __expf(-z));
}
static __device__ __forceinline__ float tanh_f(float z) {
    return 1.f - 2.f / (__expf(2.f * z) + 1.f);
}

// ---------------------------------------------------------------------------
// K0a: weights -> bf16 in MFMA-FRAGMENT order.
//  ufrag/wfrag: idx = ((ct*8+kt)*64 + lane)*8 + e
//      g = ct*16 + (lane&15), k = kt*32 + (lane>>4)*8 + e   (256x256)
//  b2frag:      idx = ((ct3*16+kt)*64 + lane)*8 + e, ct3 in [0,48)
//      g3 = ct3*16 + (lane&15), kk = kt*32 + (lane>>4)*8 + e
//      val = kk<256 ? U_iou[g3][kk] : W_iou[g3][kk-256]
// ---------------------------------------------------------------------------
__global__ void prep_weights(const float* __restrict__ Uf, const float* __restrict__ Wf,
                             const float* __restrict__ Uiou, const float* __restrict__ Wiou,
                             unsigned short* __restrict__ ufrag, unsigned short* __restrict__ wfrag,
                             unsigned short* __restrict__ b2frag) {
    const int NU = 256 * 256;
    const int NB = 768 * 512;
    int i = blockIdx.x * blockDim.x + threadIdx.x;
    const int total = NU + NU + NB;
    for (; i < total; i += gridDim.x * blockDim.x) {
        if (i < 2 * NU) {
            int j = (i < NU) ? i : i - NU;
            int e = j & 7, lane = (j >> 3) & 63, kt = (j >> 9) & 7, ct = j >> 12;
            int g = ct * 16 + (lane & 15);
            int k = kt * 32 + (lane >> 4) * 8 + e;
            if (i < NU) ufrag[j] = f2b(Uf[g * 256 + k]);
            else        wfrag[j] = f2b(Wf[g * 256 + k]);
        } else {
            int j = i - 2 * NU;
            int e = j & 7, lane = (j >> 3) & 63, kt = (j >> 9) & 15, ct3 = j >> 13;
            int g3 = ct3 * 16 + (lane & 15);
            int kk = kt * 32 + (lane >> 4) * 8 + e;
            float v = (kk < 256) ? Uiou[g3 * 256 + kk] : Wiou[g3 * 256 + kk - 256];
            b2frag[j] = f2b(v);
        }
    }
}

// ---------------------------------------------------------------------------
// K0b: XWF = x @ W_f^T + b_f  (N x 256 fp32).
// Task = (group, ct-quad); 5000 tasks, 2500 waves (grid 625), 2 tasks each.
// ---------------------------------------------------------------------------
__global__ __launch_bounds__(256, 4) void xwf_gemm(const float* __restrict__ x,
                         const unsigned short* __restrict__ wfrag,
                         const float* __restrict__ bf, float* __restrict__ xwf) {
    int lane = threadIdx.x & 63;
    int wid = (blockIdx.x * blockDim.x + threadIdx.x) >> 6;
    int nw = (gridDim.x * blockDim.x) >> 6;
    int r15 = lane & 15, q = lane >> 4;
    const int NG = N_NODES / 16;
    for (int t = wid; t < NG * 4; t += nw) {
        int grp = t >> 2, cq = t & 3;
        int n0 = grp * 16;
        const f32x4* xp = reinterpret_cast<const f32x4*>(x + ((size_t)(n0 + r15)) * 256 + q * 8);
        u16x8 afr[8];
#pragma unroll
        for (int kt = 0; kt < 8; kt++) {
            f32x4 a0 = xp[kt * 8];
            f32x4 a1 = xp[kt * 8 + 1];
            afr[kt] = pack8(a0, a1);
        }
#pragma unroll
        for (int cc = 0; cc < 4; cc++) {
            int ct = cq * 4 + cc;
            float bv = bf[ct * 16 + r15];
            f32x4 acc = {bv, bv, bv, bv};
#pragma unroll
            for (int kt = 0; kt < 8; kt++) {
                u16x8 b = *reinterpret_cast<const u16x8*>(wfrag + ((size_t)(ct * 8 + kt) * 64 + lane) * 8);
                acc = __builtin_amdgcn_mfma_f32_16x16x32_bf16(asbf(afr[kt]), asbf(b), acc, 0, 0, 0);
            }
#pragma unroll
            for (int j = 0; j < 4; j++)
                xwf[(size_t)(n0 + q * 4 + j) * 256 + ct * 16 + r15] = acc[j];
        }
    }
}

// ---------------------------------------------------------------------------
// K1: main streamer. One wave per node; grid 768 = 3 blocks/CU, one batch.
//   Phase A: mail loads (nt, coalesced) -> afr bf16 A-frags
//   Phase B: issue ALL c_mail(64)+xwf(16) scalar loads (MLP; retire before
//            any B-frag per vmcnt FIFO, covered by butterfly + first cts)
//   Phase C: butterfly h_tild -> htb (DS pipe, overlaps B)
//   Phase D: fully-unrolled 16-ct f-GEMM; epilogue uses registered cm/xv.
// ---------------------------------------------------------------------------
__global__ __launch_bounds__(256, 3) void main_cell(
        const float* __restrict__ h_mail, const float* __restrict__ c_mail,
        const float* __restrict__ time_mail, const float* __restrict__ mask,
        const float* __restrict__ xwf, const unsigned short* __restrict__ ufrag,
        unsigned short* __restrict__ htb, float* __restrict__ c_redw) {
    int lane = threadIdx.x & 63;
    int wid = (blockIdx.x * blockDim.x + threadIdx.x) >> 6;
    int nw = (gridDim.x * blockDim.x) >> 6;
    int r15 = lane & 15, q = lane >> 4;
    for (int n = wid; n < N_NODES; n += nw) {
        // --- Phase A: mail -> afr ---
        size_t rowbase = ((size_t)n * 16 + r15) * 256 + q * 8;
        const f32x4* hp = reinterpret_cast<const f32x4*>(h_mail + rowbase);
        const f32x4* tp = reinterpret_cast<const f32x4*>(time_mail + rowbase);
        u16x8 afr[8];
#pragma unroll
        for (int kt = 0; kt < 8; kt++) {
            f32x4 h0 = __builtin_nontemporal_load(hp + kt * 8);
            f32x4 h1 = __builtin_nontemporal_load(hp + kt * 8 + 1);
            f32x4 t0 = __builtin_nontemporal_load(tp + kt * 8);
            f32x4 t1 = __builtin_nontemporal_load(tp + kt * 8 + 1);
            afr[kt] = pack8(h0 + t0, h1 + t1);
        }

        // --- Phase B: batch all epilogue scalars (issued before any B-frag) ---
        const float* cmb = c_mail + ((size_t)n * 16 + q * 4) * 256 + r15;
        const float* xb  = xwf + (size_t)n * 256 + r15;
        float cm[16][4];
        float xv[16];
#pragma unroll
        for (int ct = 0; ct < 16; ct++) {
            xv[ct] = xb[ct * 16];
#pragma unroll
            for (int j = 0; j < 4; j++)
                cm[ct][j] = cmb[(size_t)j * 256 + ct * 16];
        }
        f32x4 m4 = *reinterpret_cast<const f32x4*>(mask + (size_t)n * 16 + q * 4);
        float mrow = mask[(size_t)n * 16 + r15];

        // --- Phase C: butterfly h_tild over the 16 mail rows (lane bits 0..3) ---
#pragma unroll
        for (int kt = 0; kt < 8; kt++) {
            float v[8];
#pragma unroll
            for (int e = 0; e < 8; e++) v[e] = mrow * b2f(afr[kt][e]);
#pragma unroll
            for (int m = 1; m < 16; m <<= 1) {
#pragma unroll
                for (int e = 0; e < 8; e++) v[e] += __shfl_xor(v[e], m, 64);
            }
            if (r15 == 0) {
                f32x4 w0 = {v[0], v[1], v[2], v[3]};
                f32x4 w1 = {v[4], v[5], v[6], v[7]};
                *reinterpret_cast<u16x8*>(htb + (size_t)n * 256 + kt * 32 + q * 8) = pack8(w0, w1);
            }
        }

        // --- Phase D: f-GEMM + c_red, fully unrolled, epilogue from regs ---
#pragma unroll
        for (int ct = 0; ct < 16; ct++) {
            f32x4 acc = {xv[ct], xv[ct], xv[ct], xv[ct]};
#pragma unroll
            for (int kt = 0; kt < 8; kt++) {
                u16x8 b = *reinterpret_cast<const u16x8*>(ufrag + ((size_t)(ct * 8 + kt) * 64 + lane) * 8);
                acc = __builtin_amdgcn_mfma_f32_16x16x32_bf16(asbf(afr[kt]), asbf(b), acc, 0, 0, 0);
            }
            float s = m4[0] * sigm(acc[0]) * cm[ct][0] + m4[1] * sigm(acc[1]) * cm[ct][1]
                    + m4[2] * sigm(acc[2]) * cm[ct][2] + m4[3] * sigm(acc[3]) * cm[ct][3];
            s += __shfl_xor(s, 16, 64);
            s += __shfl_xor(s, 32, 64);
            if (lane < 16) c_redw[(size_t)n * 256 + ct * 16 + lane] = s;
        }
    }
}

// ---------------------------------------------------------------------------
// K2: iou = [h_tild | x] @ [U_iou | W_iou]^T + b_iou ; gates -> h, c
// Task = (group, ct-quad); 5000 tasks, 2500 waves (grid 625), 2 tasks each.
// cr loads batched before the MFMA chain.
// ---------------------------------------------------------------------------
__global__ __launch_bounds__(256, 4) void iou_final(
        const unsigned short* __restrict__ htb, const float* __restrict__ x,
        const float* __restrict__ c_redw, const unsigned short* __restrict__ b2frag,
        const float* __restrict__ biou, float* __restrict__ out) {
    int lane = threadIdx.x & 63;
    int wid = (blockIdx.x * blockDim.x + threadIdx.x) >> 6;
    int nw = (gridDim.x * blockDim.x) >> 6;
    int r15 = lane & 15, q = lane >> 4;
    const int NG = N_NODES / 16;
    const size_t NH = (size_t)N_NODES * 256;
    for (int t = wid; t < NG * 4; t += nw) {
        int grp = t >> 2, cq = t & 3;
        int n0 = grp * 16;
        u16x8 afr[16];
#pragma unroll
        for (int kt = 0; kt < 8; kt++)
            afr[kt] = *reinterpret_cast<const u16x8*>(htb + (size_t)(n0 + r15) * 256 + kt * 32 + q * 8);
        const f32x4* xp = reinterpret_cast<const f32x4*>(x + (size_t)(n0 + r15) * 256 + q * 8);
#pragma unroll
        for (int kt = 0; kt < 8; kt++) {
            f32x4 a0 = xp[kt * 8];
            f32x4 a1 = xp[kt * 8 + 1];
            afr[8 + kt] = pack8(a0, a1);
        }
        // batch the c_red loads for all 4 col-tiles up-front (MLP)
        float cr[4][4];
#pragma unroll
        for (int cc = 0; cc < 4; cc++)
#pragma unroll
            for (int j = 0; j < 4; j++)
                cr[cc][j] = c_redw[(size_t)(n0 + q * 4 + j) * 256 + (cq * 4 + cc) * 16 + r15];
#pragma unroll
        for (int cc = 0; cc < 4; cc++) {
            int ct = cq * 4 + cc;
            float bi = biou[ct * 16 + r15];
            float bo = biou[256 + ct * 16 + r15];
            float bu = biou[512 + ct * 16 + r15];
            f32x4 ai = {bi, bi, bi, bi};
            f32x4 ao = {bo, bo, bo, bo};
            f32x4 au = {bu, bu, bu, bu};
#pragma unroll
            for (int kt = 0; kt < 16; kt++) {
                u16x8 Bi = *reinterpret_cast<const u16x8*>(b2frag + ((size_t)((ct)      * 16 + kt) * 64 + lane) * 8);
                u16x8 Bo = *reinterpret_cast<const u16x8*>(b2frag + ((size_t)((16 + ct) * 16 + kt) * 64 + lane) * 8);
                u16x8 Bu = *reinterpret_cast<const u16x8*>(b2frag + ((size_t)((32 + ct) * 16 + kt) * 64 + lane) * 8);
                ai = __builtin_amdgcn_mfma_f32_16x16x32_bf16(asbf(afr[kt]), asbf(Bi), ai, 0, 0, 0);
                ao = __builtin_amdgcn_mfma_f32_16x16x32_bf16(asbf(afr[kt]), asbf(Bo), ao, 0, 0, 0);
                au = __builtin_amdgcn_mfma_f32_16x16x32_bf16(asbf(afr[kt]), asbf(Bu), au, 0, 0, 0);
            }
#pragma unroll
            for (int j = 0; j < 4; j++) {
                size_t o = (size_t)(n0 + q * 4 + j) * 256 + ct * 16 + r15;
                float c = sigm(ai[j]) * tanh_f(au[j]) + cr[cc][j];
                float h = sigm(ao[j]) * tanh_f(c);
                __builtin_nontemporal_store(h, &out[o]);
                __builtin_nontemporal_store(c, &out[NH + o]);
            }
        }
    }
}

extern "C" void kernel_launch(void* const* d_in, const int* in_sizes, int n_in,
                              void* d_out, int out_size, void* d_ws, size_t ws_size,
                              hipStream_t stream) {
    const float* x         = (const float*)d_in[0];
    const float* h_mail    = (const float*)d_in[1];
    const float* c_mail    = (const float*)d_in[2];
    const float* time_mail = (const float*)d_in[3];
    const float* mask      = (const float*)d_in[4];
    const float* W_iou     = (const float*)d_in[5];
    const float* U_iou     = (const float*)d_in[6];
    const float* b_iou     = (const float*)d_in[7];
    const float* U_f       = (const float*)d_in[8];
    const float* W_f       = (const float*)d_in[9];
    const float* b_f       = (const float*)d_in[10];
    float* out = (float*)d_out;

    char* w = (char*)d_ws;
    unsigned short* ufrag  = (unsigned short*)(w);              // 128 KB
    unsigned short* wfrag  = (unsigned short*)(w + 131072);     // 128 KB
    unsigned short* b2frag = (unsigned short*)(w + 262144);     // 768 KB
    unsigned short* htb    = (unsigned short*)(w + 1048576);    // 10.24 MB
    float*          xwf    = (float*)(w + 11288576);            // 20.48 MB
    float*          c_redw = (float*)(w + 31768576);            // 20.48 MB

    prep_weights<<<512, 256, 0, stream>>>(U_f, W_f, U_iou, W_iou, ufrag, wfrag, b2frag);
    xwf_gemm<<<625, 256, 0, stream>>>(x, wfrag, b_f, xwf);
    main_cell<<<768, 256, 0, stream>>>(h_mail, c_mail, time_mail, mask, xwf, ufrag, htb, c_redw);
    iou_final<<<625, 256, 0, stream>>>(htb, x, c_redw, b2frag, b_iou, out);
}

// Round 5
// 1407.719 us; speedup vs baseline: 1.0283x; 1.0283x over previous
//
#include <hip/hip_runtime.h>
#include <cstdint>
#include <cstddef>

#define N_NODES 20000

typedef float f32x4 __attribute__((ext_vector_type(4)));
typedef unsigned short u16x8 __attribute__((ext_vector_type(8)));
typedef __bf16 bf16x8 __attribute__((ext_vector_type(8)));

static __device__ __forceinline__ bf16x8 asbf(u16x8 u) {
    return __builtin_bit_cast(bf16x8, u);
}
static __device__ __forceinline__ unsigned short f2b(float f) {
    return __builtin_bit_cast(unsigned short, (__bf16)f);   // RNE
}
static __device__ __forceinline__ float b2f(unsigned short u) {
    return __builtin_bit_cast(float, (unsigned)u << 16);
}
static __device__ __forceinline__ u16x8 pack8(f32x4 a, f32x4 b) {
    u16x8 r;
#pragma unroll
    for (int e = 0; e < 4; e++) {
        r[e]     = f2b(a[e]);
        r[4 + e] = f2b(b[e]);
    }
    return r;
}
static __device__ __forceinline__ float sigm(float z) {
    return 1.f / (1.f + __expf(-z));
}
static __device__ __forceinline__ float tanh_f(float z) {
    return 1.f - 2.f / (__expf(2.f * z) + 1.f);
}

// ---------------------------------------------------------------------------
// K0a: weights -> bf16 in MFMA-FRAGMENT order.
//  ufrag/wfrag: idx = ((ct*8+kt)*64 + lane)*8 + e
//      g = ct*16 + (lane&15), k = kt*32 + (lane>>4)*8 + e   (256x256)
//  b2frag:      idx = ((ct3*16+kt)*64 + lane)*8 + e, ct3 in [0,48)
//      g3 = ct3*16 + (lane&15), kk = kt*32 + (lane>>4)*8 + e
//      val = kk<256 ? U_iou[g3][kk] : W_iou[g3][kk-256]
// ---------------------------------------------------------------------------
__global__ void prep_weights(const float* __restrict__ Uf, const float* __restrict__ Wf,
                             const float* __restrict__ Uiou, const float* __restrict__ Wiou,
                             unsigned short* __restrict__ ufrag, unsigned short* __restrict__ wfrag,
                             unsigned short* __restrict__ b2frag) {
    const int NU = 256 * 256;
    const int NB = 768 * 512;
    int i = blockIdx.x * blockDim.x + threadIdx.x;
    const int total = NU + NU + NB;
    for (; i < total; i += gridDim.x * blockDim.x) {
        if (i < 2 * NU) {
            int j = (i < NU) ? i : i - NU;
            int e = j & 7, lane = (j >> 3) & 63, kt = (j >> 9) & 7, ct = j >> 12;
            int g = ct * 16 + (lane & 15);
            int k = kt * 32 + (lane >> 4) * 8 + e;
            if (i < NU) ufrag[j] = f2b(Uf[g * 256 + k]);
            else        wfrag[j] = f2b(Wf[g * 256 + k]);
        } else {
            int j = i - 2 * NU;
            int e = j & 7, lane = (j >> 3) & 63, kt = (j >> 9) & 15, ct3 = j >> 13;
            int g3 = ct3 * 16 + (lane & 15);
            int kk = kt * 32 + (lane >> 4) * 8 + e;
            float v = (kk < 256) ? Uiou[g3 * 256 + kk] : Wiou[g3 * 256 + kk - 256];
            b2frag[j] = f2b(v);
        }
    }
}

// ---------------------------------------------------------------------------
// K0b: XWF = x @ W_f^T + b_f  (N x 256 fp32).
// Task = (group, ct-quad); 5000 tasks, 5000 waves (grid 1250).
// ---------------------------------------------------------------------------
__global__ __launch_bounds__(256, 4) void xwf_gemm(const float* __restrict__ x,
                         const unsigned short* __restrict__ wfrag,
                         const float* __restrict__ bf, float* __restrict__ xwf) {
    int lane = threadIdx.x & 63;
    int wid = (blockIdx.x * blockDim.x + threadIdx.x) >> 6;
    int nw = (gridDim.x * blockDim.x) >> 6;
    int r15 = lane & 15, q = lane >> 4;
    const int NG = N_NODES / 16;
    for (int t = wid; t < NG * 4; t += nw) {
        int grp = t >> 2, cq = t & 3;
        int n0 = grp * 16;
        const f32x4* xp = reinterpret_cast<const f32x4*>(x + ((size_t)(n0 + r15)) * 256 + q * 8);
        u16x8 afr[8];
#pragma unroll
        for (int kt = 0; kt < 8; kt++) {
            f32x4 a0 = xp[kt * 8];
            f32x4 a1 = xp[kt * 8 + 1];
            afr[kt] = pack8(a0, a1);
        }
#pragma unroll
        for (int cc = 0; cc < 4; cc++) {
            int ct = cq * 4 + cc;
            float bv = bf[ct * 16 + r15];
            f32x4 acc = {bv, bv, bv, bv};
#pragma unroll
            for (int kt = 0; kt < 8; kt++) {
                u16x8 b = *reinterpret_cast<const u16x8*>(wfrag + ((size_t)(ct * 8 + kt) * 64 + lane) * 8);
                acc = __builtin_amdgcn_mfma_f32_16x16x32_bf16(asbf(afr[kt]), asbf(b), acc, 0, 0, 0);
            }
#pragma unroll
            for (int j = 0; j < 4; j++)
                xwf[(size_t)(n0 + q * 4 + j) * 256 + ct * 16 + r15] = acc[j];
        }
    }
}

// ---------------------------------------------------------------------------
// K1: main streamer. One wave per node, grid-stride; grid 2048 = 8 blocks/CU.
//   afr = bf16(h_mail + time_mail)  (nt loads)
//   h_tild via shfl butterfly -> htb
//   f = sigmoid(h_m @ U_f^T + XWF[n]); c_red = sum_k mask*f*c_mail
//   launch_bounds(256,6): VGPR cap ~85 — scheduler headroom, no spill.
// ---------------------------------------------------------------------------
__global__ __launch_bounds__(256, 6) void main_cell(
        const float* __restrict__ h_mail, const float* __restrict__ c_mail,
        const float* __restrict__ time_mail, const float* __restrict__ mask,
        const float* __restrict__ xwf, const unsigned short* __restrict__ ufrag,
        unsigned short* __restrict__ htb, float* __restrict__ c_redw) {
    int lane = threadIdx.x & 63;
    int wid = (blockIdx.x * blockDim.x + threadIdx.x) >> 6;
    int nw = (gridDim.x * blockDim.x) >> 6;
    int r15 = lane & 15, q = lane >> 4;
    for (int n = wid; n < N_NODES; n += nw) {
        size_t rowbase = ((size_t)n * 16 + r15) * 256 + q * 8;
        const f32x4* hp = reinterpret_cast<const f32x4*>(h_mail + rowbase);
        const f32x4* tp = reinterpret_cast<const f32x4*>(time_mail + rowbase);
        f32x4 m4 = *reinterpret_cast<const f32x4*>(mask + (size_t)n * 16 + q * 4);
        float mrow = mask[(size_t)n * 16 + r15];

        u16x8 afr[8];
#pragma unroll
        for (int kt = 0; kt < 8; kt++) {
            f32x4 h0 = __builtin_nontemporal_load(hp + kt * 8);
            f32x4 h1 = __builtin_nontemporal_load(hp + kt * 8 + 1);
            f32x4 t0 = __builtin_nontemporal_load(tp + kt * 8);
            f32x4 t1 = __builtin_nontemporal_load(tp + kt * 8 + 1);
            afr[kt] = pack8(h0 + t0, h1 + t1);
        }

        // h_tild: butterfly over the 16 mail rows (lane bits 0..3)
#pragma unroll
        for (int kt = 0; kt < 8; kt++) {
            float v[8];
#pragma unroll
            for (int e = 0; e < 8; e++) v[e] = mrow * b2f(afr[kt][e]);
#pragma unroll
            for (int m = 1; m < 16; m <<= 1) {
#pragma unroll
                for (int e = 0; e < 8; e++) v[e] += __shfl_xor(v[e], m, 64);
            }
            if (r15 == 0) {
                f32x4 w0 = {v[0], v[1], v[2], v[3]};
                f32x4 w1 = {v[4], v[5], v[6], v[7]};
                *reinterpret_cast<u16x8*>(htb + (size_t)n * 256 + kt * 32 + q * 8) = pack8(w0, w1);
            }
        }

        // f-GEMM + c_red (unrolled; scheduler hoists loads with VGPR headroom)
        const float* cmb = c_mail + ((size_t)n * 16 + q * 4) * 256 + r15;
        const float* xb = xwf + (size_t)n * 256 + r15;
        float mj0 = m4[0], mj1 = m4[1], mj2 = m4[2], mj3 = m4[3];
#pragma unroll
        for (int ct = 0; ct < 16; ct++) {
            float xv = xb[ct * 16];
            float cm0 = cmb[ct * 16];
            float cm1 = cmb[ct * 16 + 256];
            float cm2 = cmb[ct * 16 + 512];
            float cm3 = cmb[ct * 16 + 768];
            f32x4 acc = {xv, xv, xv, xv};
#pragma unroll
            for (int kt = 0; kt < 8; kt++) {
                u16x8 b = *reinterpret_cast<const u16x8*>(ufrag + ((size_t)(ct * 8 + kt) * 64 + lane) * 8);
                acc = __builtin_amdgcn_mfma_f32_16x16x32_bf16(asbf(afr[kt]), asbf(b), acc, 0, 0, 0);
            }
            float s = mj0 * sigm(acc[0]) * cm0 + mj1 * sigm(acc[1]) * cm1
                    + mj2 * sigm(acc[2]) * cm2 + mj3 * sigm(acc[3]) * cm3;
            s += __shfl_xor(s, 16, 64);
            s += __shfl_xor(s, 32, 64);
            if (lane < 16) c_redw[(size_t)n * 256 + ct * 16 + lane] = s;
        }
    }
}

// ---------------------------------------------------------------------------
// K2: iou = [h_tild | x] @ [U_iou | W_iou]^T + b_iou ; gates -> h, c
// Task = (group, ct-quad); 5000 tasks, 5000 waves (grid 1250).
// ---------------------------------------------------------------------------
__global__ __launch_bounds__(256, 4) void iou_final(
        const unsigned short* __restrict__ htb, const float* __restrict__ x,
        const float* __restrict__ c_redw, const unsigned short* __restrict__ b2frag,
        const float* __restrict__ biou, float* __restrict__ out) {
    int lane = threadIdx.x & 63;
    int wid = (blockIdx.x * blockDim.x + threadIdx.x) >> 6;
    int nw = (gridDim.x * blockDim.x) >> 6;
    int r15 = lane & 15, q = lane >> 4;
    const int NG = N_NODES / 16;
    const size_t NH = (size_t)N_NODES * 256;
    for (int t = wid; t < NG * 4; t += nw) {
        int grp = t >> 2, cq = t & 3;
        int n0 = grp * 16;
        u16x8 afr[16];
#pragma unroll
        for (int kt = 0; kt < 8; kt++)
            afr[kt] = *reinterpret_cast<const u16x8*>(htb + (size_t)(n0 + r15) * 256 + kt * 32 + q * 8);
        const f32x4* xp = reinterpret_cast<const f32x4*>(x + (size_t)(n0 + r15) * 256 + q * 8);
#pragma unroll
        for (int kt = 0; kt < 8; kt++) {
            f32x4 a0 = xp[kt * 8];
            f32x4 a1 = xp[kt * 8 + 1];
            afr[8 + kt] = pack8(a0, a1);
        }
#pragma unroll
        for (int cc = 0; cc < 4; cc++) {
            int ct = cq * 4 + cc;
            float cr[4];
#pragma unroll
            for (int j = 0; j < 4; j++)
                cr[j] = c_redw[(size_t)(n0 + q * 4 + j) * 256 + ct * 16 + r15];
            float bi = biou[ct * 16 + r15];
            float bo = biou[256 + ct * 16 + r15];
            float bu = biou[512 + ct * 16 + r15];
            f32x4 ai = {bi, bi, bi, bi};
            f32x4 ao = {bo, bo, bo, bo};
            f32x4 au = {bu, bu, bu, bu};
#pragma unroll
            for (int kt = 0; kt < 16; kt++) {
                u16x8 Bi = *reinterpret_cast<const u16x8*>(b2frag + ((size_t)((ct)      * 16 + kt) * 64 + lane) * 8);
                u16x8 Bo = *reinterpret_cast<const u16x8*>(b2frag + ((size_t)((16 + ct) * 16 + kt) * 64 + lane) * 8);
                u16x8 Bu = *reinterpret_cast<const u16x8*>(b2frag + ((size_t)((32 + ct) * 16 + kt) * 64 + lane) * 8);
                ai = __builtin_amdgcn_mfma_f32_16x16x32_bf16(asbf(afr[kt]), asbf(Bi), ai, 0, 0, 0);
                ao = __builtin_amdgcn_mfma_f32_16x16x32_bf16(asbf(afr[kt]), asbf(Bo), ao, 0, 0, 0);
                au = __builtin_amdgcn_mfma_f32_16x16x32_bf16(asbf(afr[kt]), asbf(Bu), au, 0, 0, 0);
            }
#pragma unroll
            for (int j = 0; j < 4; j++) {
                size_t o = (size_t)(n0 + q * 4 + j) * 256 + ct * 16 + r15;
                float c = sigm(ai[j]) * tanh_f(au[j]) + cr[j];
                float h = sigm(ao[j]) * tanh_f(c);
                __builtin_nontemporal_store(h, &out[o]);
                __builtin_nontemporal_store(c, &out[NH + o]);
            }
        }
    }
}

extern "C" void kernel_launch(void* const* d_in, const int* in_sizes, int n_in,
                              void* d_out, int out_size, void* d_ws, size_t ws_size,
                              hipStream_t stream) {
    const float* x         = (const float*)d_in[0];
    const float* h_mail    = (const float*)d_in[1];
    const float* c_mail    = (const float*)d_in[2];
    const float* time_mail = (const float*)d_in[3];
    const float* mask      = (const float*)d_in[4];
    const float* W_iou     = (const float*)d_in[5];
    const float* U_iou     = (const float*)d_in[6];
    const float* b_iou     = (const float*)d_in[7];
    const float* U_f       = (const float*)d_in[8];
    const float* W_f       = (const float*)d_in[9];
    const float* b_f       = (const float*)d_in[10];
    float* out = (float*)d_out;

    char* w = (char*)d_ws;
    unsigned short* ufrag  = (unsigned short*)(w);              // 128 KB
    unsigned short* wfrag  = (unsigned short*)(w + 131072);     // 128 KB
    unsigned short* b2frag = (unsigned short*)(w + 262144);     // 768 KB
    unsigned short* htb    = (unsigned short*)(w + 1048576);    // 10.24 MB
    float*          xwf    = (float*)(w + 11288576);            // 20.48 MB
    float*          c_redw = (float*)(w + 31768576);            // 20.48 MB

    prep_weights<<<512, 256, 0, stream>>>(U_f, W_f, U_iou, W_iou, ufrag, wfrag, b2frag);
    xwf_gemm<<<1250, 256, 0, stream>>>(x, wfrag, b_f, xwf);
    main_cell<<<2048, 256, 0, stream>>>(h_mail, c_mail, time_mail, mask, xwf, ufrag, htb, c_redw);
    iou_final<<<1250, 256, 0, stream>>>(htb, x, c_redw, b2frag, b_iou, out);
}

// Round 6
// 484.766 us; speedup vs baseline: 2.9860x; 2.9039x over previous
//
#include <hip/hip_runtime.h>
#include <cstdint>
#include <cstddef>

#define N_NODES 20000

typedef float f32x4 __attribute__((ext_vector_type(4)));
typedef unsigned short u16x8 __attribute__((ext_vector_type(8)));
typedef unsigned short u16x4 __attribute__((ext_vector_type(4)));
typedef __bf16 bf16x8 __attribute__((ext_vector_type(8)));

static __device__ __forceinline__ bf16x8 asbf(u16x8 u) {
    return __builtin_bit_cast(bf16x8, u);
}
static __device__ __forceinline__ unsigned short f2b(float f) {
    return __builtin_bit_cast(unsigned short, (__bf16)f);   // RNE
}
static __device__ __forceinline__ float b2f(unsigned short u) {
    return __builtin_bit_cast(float, (unsigned)u << 16);
}
static __device__ __forceinline__ u16x8 pack8(f32x4 a, f32x4 b) {
    u16x8 r;
#pragma unroll
    for (int e = 0; e < 4; e++) {
        r[e]     = f2b(a[e]);
        r[4 + e] = f2b(b[e]);
    }
    return r;
}
static __device__ __forceinline__ float sigm(float z) {
    return 1.f / (1.f + __expf(-z));
}
static __device__ __forceinline__ float tanh_f(float z) {
    return 1.f - 2.f / (__expf(2.f * z) + 1.f);
}

// ---------------------------------------------------------------------------
// K0a: weights -> bf16 in MFMA-FRAGMENT order (unchanged).
// ---------------------------------------------------------------------------
__global__ void prep_weights(const float* __restrict__ Uf, const float* __restrict__ Wf,
                             const float* __restrict__ Uiou, const float* __restrict__ Wiou,
                             unsigned short* __restrict__ ufrag, unsigned short* __restrict__ wfrag,
                             unsigned short* __restrict__ b2frag) {
    const int NU = 256 * 256;
    const int NB = 768 * 512;
    int i = blockIdx.x * blockDim.x + threadIdx.x;
    const int total = NU + NU + NB;
    for (; i < total; i += gridDim.x * blockDim.x) {
        if (i < 2 * NU) {
            int j = (i < NU) ? i : i - NU;
            int e = j & 7, lane = (j >> 3) & 63, kt = (j >> 9) & 7, ct = j >> 12;
            int g = ct * 16 + (lane & 15);
            int k = kt * 32 + (lane >> 4) * 8 + e;
            if (i < NU) ufrag[j] = f2b(Uf[g * 256 + k]);
            else        wfrag[j] = f2b(Wf[g * 256 + k]);
        } else {
            int j = i - 2 * NU;
            int e = j & 7, lane = (j >> 3) & 63, kt = (j >> 9) & 15, ct3 = j >> 13;
            int g3 = ct3 * 16 + (lane & 15);
            int kk = kt * 32 + (lane >> 4) * 8 + e;
            float v = (kk < 256) ? Uiou[g3 * 256 + kk] : Wiou[g3 * 256 + kk - 256];
            b2frag[j] = f2b(v);
        }
    }
}

// ---------------------------------------------------------------------------
// K0b: XWF = x @ W_f^T + b_f  (N x 256 fp32). Unchanged (grid 1250).
// ---------------------------------------------------------------------------
__global__ __launch_bounds__(256, 4) void xwf_gemm(const float* __restrict__ x,
                         const unsigned short* __restrict__ wfrag,
                         const float* __restrict__ bf, float* __restrict__ xwf) {
    int lane = threadIdx.x & 63;
    int wid = (blockIdx.x * blockDim.x + threadIdx.x) >> 6;
    int nw = (gridDim.x * blockDim.x) >> 6;
    int r15 = lane & 15, q = lane >> 4;
    const int NG = N_NODES / 16;
    for (int t = wid; t < NG * 4; t += nw) {
        int grp = t >> 2, cq = t & 3;
        int n0 = grp * 16;
        const f32x4* xp = reinterpret_cast<const f32x4*>(x + ((size_t)(n0 + r15)) * 256 + q * 8);
        u16x8 afr[8];
#pragma unroll
        for (int kt = 0; kt < 8; kt++) {
            f32x4 a0 = xp[kt * 8];
            f32x4 a1 = xp[kt * 8 + 1];
            afr[kt] = pack8(a0, a1);
        }
#pragma unroll
        for (int cc = 0; cc < 4; cc++) {
            int ct = cq * 4 + cc;
            float bv = bf[ct * 16 + r15];
            f32x4 acc = {bv, bv, bv, bv};
#pragma unroll
            for (int kt = 0; kt < 8; kt++) {
                u16x8 b = *reinterpret_cast<const u16x8*>(wfrag + ((size_t)(ct * 8 + kt) * 64 + lane) * 8);
                acc = __builtin_amdgcn_mfma_f32_16x16x32_bf16(asbf(afr[kt]), asbf(b), acc, 0, 0, 0);
            }
#pragma unroll
            for (int j = 0; j < 4; j++)
                xwf[(size_t)(n0 + q * 4 + j) * 256 + ct * 16 + r15] = acc[j];
        }
    }
}

// ---------------------------------------------------------------------------
// K1a: mail streamer + f-GEMM (NO c_mail / NO xwf — pure L2 inner loop).
//   afr = bf16(h_mail + time_mail); h_tild butterfly -> htb;
//   S = h_m @ U_f^T (pre-activation, bf16) -> Sws[(n-nbeg)][k][g]
// ---------------------------------------------------------------------------
__global__ __launch_bounds__(256, 4) void mail_gemm(
        const float* __restrict__ h_mail, const float* __restrict__ time_mail,
        const float* __restrict__ mask, const unsigned short* __restrict__ ufrag,
        unsigned short* __restrict__ htb, unsigned short* __restrict__ Sws,
        int nbeg, int nend) {
    int lane = threadIdx.x & 63;
    int wid = (blockIdx.x * blockDim.x + threadIdx.x) >> 6;
    int nw = (gridDim.x * blockDim.x) >> 6;
    int r15 = lane & 15, q = lane >> 4;
    for (int n = nbeg + wid; n < nend; n += nw) {
        size_t rowbase = ((size_t)n * 16 + r15) * 256 + q * 8;
        const f32x4* hp = reinterpret_cast<const f32x4*>(h_mail + rowbase);
        const f32x4* tp = reinterpret_cast<const f32x4*>(time_mail + rowbase);
        float mrow = mask[(size_t)n * 16 + r15];

        u16x8 afr[8];
#pragma unroll
        for (int kt = 0; kt < 8; kt++) {
            f32x4 h0 = __builtin_nontemporal_load(hp + kt * 8);
            f32x4 h1 = __builtin_nontemporal_load(hp + kt * 8 + 1);
            f32x4 t0 = __builtin_nontemporal_load(tp + kt * 8);
            f32x4 t1 = __builtin_nontemporal_load(tp + kt * 8 + 1);
            afr[kt] = pack8(h0 + t0, h1 + t1);
        }

        // h_tild: butterfly over the 16 mail rows (lane bits 0..3)
#pragma unroll
        for (int kt = 0; kt < 8; kt++) {
            float v[8];
#pragma unroll
            for (int e = 0; e < 8; e++) v[e] = mrow * b2f(afr[kt][e]);
#pragma unroll
            for (int m = 1; m < 16; m <<= 1) {
#pragma unroll
                for (int e = 0; e < 8; e++) v[e] += __shfl_xor(v[e], m, 64);
            }
            if (r15 == 0) {
                f32x4 w0 = {v[0], v[1], v[2], v[3]};
                f32x4 w1 = {v[4], v[5], v[6], v[7]};
                *reinterpret_cast<u16x8*>(htb + (size_t)n * 256 + kt * 32 + q * 8) = pack8(w0, w1);
            }
        }

        // f-GEMM: only L2-resident ufrag in the loop; store pre-activation S.
        unsigned short* Sb = Sws + ((size_t)(n - nbeg) * 16 + q * 4) * 256 + r15;
        for (int ct = 0; ct < 16; ct++) {
            f32x4 acc = {0.f, 0.f, 0.f, 0.f};
#pragma unroll
            for (int kt = 0; kt < 8; kt++) {
                u16x8 b = *reinterpret_cast<const u16x8*>(ufrag + ((size_t)(ct * 8 + kt) * 64 + lane) * 8);
                acc = __builtin_amdgcn_mfma_f32_16x16x32_bf16(asbf(afr[kt]), asbf(b), acc, 0, 0, 0);
            }
#pragma unroll
            for (int j = 0; j < 4; j++)
                Sb[(size_t)j * 256 + ct * 16] = f2b(acc[j]);
        }
    }
}

// ---------------------------------------------------------------------------
// K1b: pure streaming epilogue. One wave per node; lane owns 4 columns.
//   c_red[g] = sum_k mask[k] * sigm(S[k][g] + xwf[n][g]) * c_mail[k][g]
//   S plain loads (L2/L3-warm from K1a); c_mail nt (stream-once).
// ---------------------------------------------------------------------------
__global__ __launch_bounds__(256, 4) void c_red_epi(
        const unsigned short* __restrict__ Sws, const float* __restrict__ c_mail,
        const float* __restrict__ xwf, const float* __restrict__ mask,
        float* __restrict__ c_redw, int nbeg, int nend) {
    int lane = threadIdx.x & 63;
    int wid = (blockIdx.x * blockDim.x + threadIdx.x) >> 6;
    int nw = (gridDim.x * blockDim.x) >> 6;
    for (int n = nbeg + wid; n < nend; n += nw) {
        f32x4 xv = *reinterpret_cast<const f32x4*>(xwf + (size_t)n * 256 + lane * 4);
        const unsigned short* Sb = Sws + (size_t)(n - nbeg) * 4096 + lane * 4;
        const float* cb = c_mail + (size_t)n * 4096 + lane * 4;
        const float* mb = mask + (size_t)n * 16;
        f32x4 acc = {0.f, 0.f, 0.f, 0.f};
#pragma unroll 4
        for (int r = 0; r < 16; r++) {
            u16x4 sv = *reinterpret_cast<const u16x4*>(Sb + (size_t)r * 256);
            f32x4 cv = __builtin_nontemporal_load(
                reinterpret_cast<const f32x4*>(cb + (size_t)r * 256));
            float m = mb[r];
#pragma unroll
            for (int e = 0; e < 4; e++)
                acc[e] += m * sigm(b2f(sv[e]) + xv[e]) * cv[e];
        }
        *reinterpret_cast<f32x4*>(c_redw + (size_t)n * 256 + lane * 4) = acc;
    }
}

// ---------------------------------------------------------------------------
// Fallback (small ws): R3 monolithic main_cell (427 us known-good profile).
// ---------------------------------------------------------------------------
__global__ __launch_bounds__(256, 4) void main_cell_mono(
        const float* __restrict__ h_mail, const float* __restrict__ c_mail,
        const float* __restrict__ time_mail, const float* __restrict__ mask,
        const float* __restrict__ xwf, const unsigned short* __restrict__ ufrag,
        unsigned short* __restrict__ htb, float* __restrict__ c_redw) {
    int lane = threadIdx.x & 63;
    int wid = (blockIdx.x * blockDim.x + threadIdx.x) >> 6;
    int nw = (gridDim.x * blockDim.x) >> 6;
    int r15 = lane & 15, q = lane >> 4;
    for (int n = wid; n < N_NODES; n += nw) {
        size_t rowbase = ((size_t)n * 16 + r15) * 256 + q * 8;
        const f32x4* hp = reinterpret_cast<const f32x4*>(h_mail + rowbase);
        const f32x4* tp = reinterpret_cast<const f32x4*>(time_mail + rowbase);
        f32x4 m4 = *reinterpret_cast<const f32x4*>(mask + (size_t)n * 16 + q * 4);
        float mrow = mask[(size_t)n * 16 + r15];
        u16x8 afr[8];
#pragma unroll
        for (int kt = 0; kt < 8; kt++) {
            f32x4 h0 = __builtin_nontemporal_load(hp + kt * 8);
            f32x4 h1 = __builtin_nontemporal_load(hp + kt * 8 + 1);
            f32x4 t0 = __builtin_nontemporal_load(tp + kt * 8);
            f32x4 t1 = __builtin_nontemporal_load(tp + kt * 8 + 1);
            afr[kt] = pack8(h0 + t0, h1 + t1);
        }
#pragma unroll
        for (int kt = 0; kt < 8; kt++) {
            float v[8];
#pragma unroll
            for (int e = 0; e < 8; e++) v[e] = mrow * b2f(afr[kt][e]);
#pragma unroll
            for (int m = 1; m < 16; m <<= 1) {
#pragma unroll
                for (int e = 0; e < 8; e++) v[e] += __shfl_xor(v[e], m, 64);
            }
            if (r15 == 0) {
                f32x4 w0 = {v[0], v[1], v[2], v[3]};
                f32x4 w1 = {v[4], v[5], v[6], v[7]};
                *reinterpret_cast<u16x8*>(htb + (size_t)n * 256 + kt * 32 + q * 8) = pack8(w0, w1);
            }
        }
        const float* cmb = c_mail + ((size_t)n * 16 + q * 4) * 256 + r15;
        const float* xb = xwf + (size_t)n * 256 + r15;
        for (int ct = 0; ct < 16; ct++) {
            float xv = xb[ct * 16];
            float cm0 = cmb[ct * 16];
            float cm1 = cmb[ct * 16 + 256];
            float cm2 = cmb[ct * 16 + 512];
            float cm3 = cmb[ct * 16 + 768];
            f32x4 acc = {xv, xv, xv, xv};
#pragma unroll
            for (int kt = 0; kt < 8; kt++) {
                u16x8 b = *reinterpret_cast<const u16x8*>(ufrag + ((size_t)(ct * 8 + kt) * 64 + lane) * 8);
                acc = __builtin_amdgcn_mfma_f32_16x16x32_bf16(asbf(afr[kt]), asbf(b), acc, 0, 0, 0);
            }
            float s = m4[0] * sigm(acc[0]) * cm0 + m4[1] * sigm(acc[1]) * cm1
                    + m4[2] * sigm(acc[2]) * cm2 + m4[3] * sigm(acc[3]) * cm3;
            s += __shfl_xor(s, 16, 64);
            s += __shfl_xor(s, 32, 64);
            if (lane < 16) c_redw[(size_t)n * 256 + ct * 16 + lane] = s;
        }
    }
}

// ---------------------------------------------------------------------------
// K2: iou = [h_tild | x] @ [U_iou | W_iou]^T + b_iou ; gates -> h, c (grid 1250)
// ---------------------------------------------------------------------------
__global__ __launch_bounds__(256, 4) void iou_final(
        const unsigned short* __restrict__ htb, const float* __restrict__ x,
        const float* __restrict__ c_redw, const unsigned short* __restrict__ b2frag,
        const float* __restrict__ biou, float* __restrict__ out) {
    int lane = threadIdx.x & 63;
    int wid = (blockIdx.x * blockDim.x + threadIdx.x) >> 6;
    int nw = (gridDim.x * blockDim.x) >> 6;
    int r15 = lane & 15, q = lane >> 4;
    const int NG = N_NODES / 16;
    const size_t NH = (size_t)N_NODES * 256;
    for (int t = wid; t < NG * 4; t += nw) {
        int grp = t >> 2, cq = t & 3;
        int n0 = grp * 16;
        u16x8 afr[16];
#pragma unroll
        for (int kt = 0; kt < 8; kt++)
            afr[kt] = *reinterpret_cast<const u16x8*>(htb + (size_t)(n0 + r15) * 256 + kt * 32 + q * 8);
        const f32x4* xp = reinterpret_cast<const f32x4*>(x + (size_t)(n0 + r15) * 256 + q * 8);
#pragma unroll
        for (int kt = 0; kt < 8; kt++) {
            f32x4 a0 = xp[kt * 8];
            f32x4 a1 = xp[kt * 8 + 1];
            afr[8 + kt] = pack8(a0, a1);
        }
#pragma unroll
        for (int cc = 0; cc < 4; cc++) {
            int ct = cq * 4 + cc;
            float cr[4];
#pragma unroll
            for (int j = 0; j < 4; j++)
                cr[j] = c_redw[(size_t)(n0 + q * 4 + j) * 256 + ct * 16 + r15];
            float bi = biou[ct * 16 + r15];
            float bo = biou[256 + ct * 16 + r15];
            float bu = biou[512 + ct * 16 + r15];
            f32x4 ai = {bi, bi, bi, bi};
            f32x4 ao = {bo, bo, bo, bo};
            f32x4 au = {bu, bu, bu, bu};
#pragma unroll
            for (int kt = 0; kt < 16; kt++) {
                u16x8 Bi = *reinterpret_cast<const u16x8*>(b2frag + ((size_t)((ct)      * 16 + kt) * 64 + lane) * 8);
                u16x8 Bo = *reinterpret_cast<const u16x8*>(b2frag + ((size_t)((16 + ct) * 16 + kt) * 64 + lane) * 8);
                u16x8 Bu = *reinterpret_cast<const u16x8*>(b2frag + ((size_t)((32 + ct) * 16 + kt) * 64 + lane) * 8);
                ai = __builtin_amdgcn_mfma_f32_16x16x32_bf16(asbf(afr[kt]), asbf(Bi), ai, 0, 0, 0);
                ao = __builtin_amdgcn_mfma_f32_16x16x32_bf16(asbf(afr[kt]), asbf(Bo), ao, 0, 0, 0);
                au = __builtin_amdgcn_mfma_f32_16x16x32_bf16(asbf(afr[kt]), asbf(Bu), au, 0, 0, 0);
            }
#pragma unroll
            for (int j = 0; j < 4; j++) {
                size_t o = (size_t)(n0 + q * 4 + j) * 256 + ct * 16 + r15;
                float c = sigm(ai[j]) * tanh_f(au[j]) + cr[j];
                float h = sigm(ao[j]) * tanh_f(c);
                __builtin_nontemporal_store(h, &out[o]);
                __builtin_nontemporal_store(c, &out[NH + o]);
            }
        }
    }
}

extern "C" void kernel_launch(void* const* d_in, const int* in_sizes, int n_in,
                              void* d_out, int out_size, void* d_ws, size_t ws_size,
                              hipStream_t stream) {
    const float* x         = (const float*)d_in[0];
    const float* h_mail    = (const float*)d_in[1];
    const float* c_mail    = (const float*)d_in[2];
    const float* time_mail = (const float*)d_in[3];
    const float* mask      = (const float*)d_in[4];
    const float* W_iou     = (const float*)d_in[5];
    const float* U_iou     = (const float*)d_in[6];
    const float* b_iou     = (const float*)d_in[7];
    const float* U_f       = (const float*)d_in[8];
    const float* W_f       = (const float*)d_in[9];
    const float* b_f       = (const float*)d_in[10];
    float* out = (float*)d_out;

    char* w = (char*)d_ws;
    unsigned short* ufrag  = (unsigned short*)(w);              // 128 KB
    unsigned short* wfrag  = (unsigned short*)(w + 131072);     // 128 KB
    unsigned short* b2frag = (unsigned short*)(w + 262144);     // 768 KB
    unsigned short* htb    = (unsigned short*)(w + 1048576);    // 10.24 MB
    float*          xwf    = (float*)(w + 11288576);            // 20.48 MB
    float*          c_redw = (float*)(w + 31768576);            // 20.48 MB
    const size_t base = 52248576;
    unsigned short* Sws    = (unsigned short*)(w + base);       // S chunks (bf16)

    prep_weights<<<512, 256, 0, stream>>>(U_f, W_f, U_iou, W_iou, ufrag, wfrag, b2frag);
    xwf_gemm<<<1250, 256, 0, stream>>>(x, wfrag, b_f, xwf);

    // S chunk sizing from ws_size (deterministic: depends only on ws_size).
    const size_t per_node = 16 * 256 * sizeof(unsigned short);  // 8192 B
    size_t avail = (ws_size > base) ? (ws_size - base) : 0;
    int chunk = (int)((avail / per_node < (size_t)N_NODES) ? (avail / per_node) : (size_t)N_NODES);
    if (chunk > 10000) chunk = 10000;   // 2 chunks of 82 MB: better L3 retention

    if (chunk >= 2000) {
        for (int s = 0; s < N_NODES; s += chunk) {
            int e = (s + chunk < N_NODES) ? (s + chunk) : N_NODES;
            int cnt = e - s;
            int grid = (cnt + 3) / 4;
            if (grid > 2500) grid = 2500;
            mail_gemm<<<grid, 256, 0, stream>>>(h_mail, time_mail, mask, ufrag, htb, Sws, s, e);
            c_red_epi<<<grid, 256, 0, stream>>>(Sws, c_mail, xwf, mask, c_redw, s, e);
        }
    } else {
        main_cell_mono<<<2500, 256, 0, stream>>>(h_mail, c_mail, time_mail, mask, xwf, ufrag, htb, c_redw);
    }

    iou_final<<<1250, 256, 0, stream>>>(htb, x, c_redw, b2frag, b_iou, out);
}